// Round 1
// baseline (437.785 us; speedup 1.0000x reference)
//
#include <hip/hip_runtime.h>

#define BATCH 256
#define NPTS 65536
#define NT 1024
#define NWAVES (NT / 64)

// ---------------------------------------------------------------------------
// Kernel 1: one block per batch. Stream src(3 rows), tgt(3 rows), weight and
// accumulate 22 sums:
//  [0..2]  = sum s_i            [3..5]  = sum t_j          [6] = sum w
//  [7..9]  = sum w*s_i          [10..12]= sum w*t_j
//  [13..21]= sum w*s_i*t_j  (i*3+j)
// Writes 22 floats per batch to ws.
// ---------------------------------------------------------------------------
__global__ __launch_bounds__(NT, 1) void svdhead_reduce(
    const float* __restrict__ src, const float* __restrict__ tgt,
    const float* __restrict__ weight, float* __restrict__ ws)
{
    const int b   = blockIdx.x;
    const int tid = threadIdx.x;
    const int NV  = NPTS / 4;

    const float4* sp = (const float4*)(src + (size_t)b * 3 * NPTS);
    const float4* tp = (const float4*)(tgt + (size_t)b * 3 * NPTS);
    const float4* wp = (const float4*)(weight + (size_t)b * NPTS);

    float acc[22];
#pragma unroll
    for (int i = 0; i < 22; i++) acc[i] = 0.f;

    for (int k = tid; k < NV; k += NT) {
        float4 w4 = wp[k];
        float4 s0 = sp[k];
        float4 s1 = sp[k + NV];
        float4 s2 = sp[k + 2 * NV];
        float4 t0 = tp[k];
        float4 t1 = tp[k + NV];
        float4 t2 = tp[k + 2 * NV];
#define ACC1(C) do {                                                    \
        float wv = w4.C;                                                \
        float a0 = s0.C, a1 = s1.C, a2 = s2.C;                          \
        float c0 = t0.C, c1 = t1.C, c2 = t2.C;                          \
        acc[0] += a0;  acc[1] += a1;  acc[2] += a2;                     \
        acc[3] += c0;  acc[4] += c1;  acc[5] += c2;                     \
        acc[6] += wv;                                                   \
        float wa0 = wv * a0, wa1 = wv * a1, wa2 = wv * a2;              \
        acc[7]  += wa0; acc[8]  += wa1; acc[9]  += wa2;                 \
        acc[10] += wv * c0; acc[11] += wv * c1; acc[12] += wv * c2;     \
        acc[13] += wa0 * c0; acc[14] += wa0 * c1; acc[15] += wa0 * c2;  \
        acc[16] += wa1 * c0; acc[17] += wa1 * c1; acc[18] += wa1 * c2;  \
        acc[19] += wa2 * c0; acc[20] += wa2 * c1; acc[21] += wa2 * c2;  \
    } while (0)
        ACC1(x); ACC1(y); ACC1(z); ACC1(w);
#undef ACC1
    }

    // wave-level reduce (64 lanes)
#pragma unroll
    for (int off = 32; off > 0; off >>= 1) {
#pragma unroll
        for (int i = 0; i < 22; i++) acc[i] += __shfl_down(acc[i], off, 64);
    }

    __shared__ float red[NWAVES][22];
    const int wave = tid >> 6;
    const int lane = tid & 63;
    if (lane == 0) {
#pragma unroll
        for (int i = 0; i < 22; i++) red[wave][i] = acc[i];
    }
    __syncthreads();

    if (tid < 22) {
        float s = 0.f;
#pragma unroll
        for (int wv = 0; wv < NWAVES; wv++) s += red[wv][tid];
        ws[(size_t)b * 22 + tid] = s;
    }
}

// ---------------------------------------------------------------------------
// Kernel 2: one thread per batch. fp64 3x3 Kabsch solve:
//   H from the 22 sums; Jacobi eigendecomp of A = H^T H -> V, lambda;
//   U = H V / sigma (cross fallback); R = V diag(1,1,sign(detH)) U^T;
//   outputs R^T (B,3,3) then t_out = -R^T (tbar - R sbar)  (B,3).
// ---------------------------------------------------------------------------
__global__ __launch_bounds__(256, 1) void svdhead_solve(
    const float* __restrict__ ws, float* __restrict__ out)
{
    const int b = blockIdx.x * blockDim.x + threadIdx.x;
    if (b >= BATCH) return;

    double S[22];
#pragma unroll
    for (int i = 0; i < 22; i++) S[i] = (double)ws[(size_t)b * 22 + i];

    const double invN = 1.0 / (double)NPTS;
    double ms[3] = { S[0] * invN, S[1] * invN, S[2] * invN };
    double mt[3] = { S[3] * invN, S[4] * invN, S[5] * invN };
    const double sw = S[6];

    double H[3][3];
    for (int i = 0; i < 3; i++)
        for (int j = 0; j < 3; j++)
            H[i][j] = S[13 + i * 3 + j] - ms[i] * S[10 + j] - mt[j] * S[7 + i]
                      + ms[i] * mt[j] * sw;

    // A = H^T H (symmetric PSD)
    double A[3][3];
    for (int i = 0; i < 3; i++)
        for (int j = 0; j < 3; j++) {
            double s = 0.0;
            for (int k = 0; k < 3; k++) s += H[k][i] * H[k][j];
            A[i][j] = s;
        }

    // cyclic Jacobi eigendecomposition, eigenvectors in columns of V
    double V[3][3] = { {1,0,0}, {0,1,0}, {0,0,1} };
    for (int sweep = 0; sweep < 30; sweep++) {
        double off  = fabs(A[0][1]) + fabs(A[0][2]) + fabs(A[1][2]);
        double diag = fabs(A[0][0]) + fabs(A[1][1]) + fabs(A[2][2]);
        if (off <= 1e-13 * diag || off == 0.0) break;
        for (int p = 0; p < 2; p++)
            for (int q = p + 1; q < 3; q++) {
                double apq = A[p][q];
                if (fabs(apq) < 1e-300) continue;
                double tau = (A[q][q] - A[p][p]) / (2.0 * apq);
                double t = (tau >= 0.0 ? 1.0 : -1.0) / (fabs(tau) + sqrt(1.0 + tau * tau));
                double c = 1.0 / sqrt(1.0 + t * t);
                double s_ = t * c;
                for (int k = 0; k < 3; k++) {        // A <- A J (cols p,q)
                    double akp = A[k][p], akq = A[k][q];
                    A[k][p] = c * akp - s_ * akq;
                    A[k][q] = s_ * akp + c * akq;
                }
                for (int k = 0; k < 3; k++) {        // A <- J^T A (rows p,q)
                    double apk = A[p][k], aqk = A[q][k];
                    A[p][k] = c * apk - s_ * aqk;
                    A[q][k] = s_ * apk + c * aqk;
                }
                for (int k = 0; k < 3; k++) {        // V <- V J
                    double vkp = V[k][p], vkq = V[k][q];
                    V[k][p] = c * vkp - s_ * vkq;
                    V[k][q] = s_ * vkp + c * vkq;
                }
            }
    }

    // sort eigenvalues descending, permute V columns
    double lam[3] = { A[0][0], A[1][1], A[2][2] };
    int id[3] = { 0, 1, 2 };
    if (lam[id[0]] < lam[id[1]]) { int t = id[0]; id[0] = id[1]; id[1] = t; }
    if (lam[id[0]] < lam[id[2]]) { int t = id[0]; id[0] = id[2]; id[2] = t; }
    if (lam[id[1]] < lam[id[2]]) { int t = id[1]; id[1] = id[2]; id[2] = t; }
    double Vs[3][3];
    for (int k = 0; k < 3; k++)
        for (int i = 0; i < 3; i++) Vs[i][k] = V[i][id[k]];

    // U columns: u_k = H v_k / sigma_k
    double U[3][3], sig[3];
    for (int k = 0; k < 3; k++) {
        double u0 = H[0][0] * Vs[0][k] + H[0][1] * Vs[1][k] + H[0][2] * Vs[2][k];
        double u1 = H[1][0] * Vs[0][k] + H[1][1] * Vs[1][k] + H[1][2] * Vs[2][k];
        double u2 = H[2][0] * Vs[0][k] + H[2][1] * Vs[1][k] + H[2][2] * Vs[2][k];
        sig[k] = sqrt(u0 * u0 + u1 * u1 + u2 * u2);
        U[0][k] = u0; U[1][k] = u1; U[2][k] = u2;
    }
    double smax = (sig[0] > 1e-300) ? sig[0] : 1e-300;

    if (sig[0] > 0.0) {
        U[0][0] /= sig[0]; U[1][0] /= sig[0]; U[2][0] /= sig[0];
    } else {  // H == 0: arbitrary orthonormal U
        U[0][0] = 1; U[1][0] = 0; U[2][0] = 0;
    }
    if (sig[1] > 1e-12 * smax) {
        U[0][1] /= sig[1]; U[1][1] /= sig[1]; U[2][1] /= sig[1];
    } else {  // pick unit vector orthogonal to col 0
        double ax = fabs(U[0][0]), ay = fabs(U[1][0]), az = fabs(U[2][0]);
        double e0, e1, e2;
        if (ax <= ay && ax <= az)      { e0 = 1; e1 = 0; e2 = 0; }
        else if (ay <= az)             { e0 = 0; e1 = 1; e2 = 0; }
        else                           { e0 = 0; e1 = 0; e2 = 1; }
        double cx = U[1][0] * e2 - U[2][0] * e1;
        double cy = U[2][0] * e0 - U[0][0] * e2;
        double cz = U[0][0] * e1 - U[1][0] * e0;
        double n = sqrt(cx * cx + cy * cy + cz * cz);
        U[0][1] = cx / n; U[1][1] = cy / n; U[2][1] = cz / n;
    }
    if (sig[2] > 1e-12 * smax) {
        U[0][2] /= sig[2]; U[1][2] /= sig[2]; U[2][2] /= sig[2];
    } else {  // cross product completion
        U[0][2] = U[1][0] * U[2][1] - U[2][0] * U[1][1];
        U[1][2] = U[2][0] * U[0][1] - U[0][0] * U[2][1];
        U[2][2] = U[0][0] * U[1][1] - U[1][0] * U[0][1];
    }

    double detH = H[0][0] * (H[1][1] * H[2][2] - H[1][2] * H[2][1])
                - H[0][1] * (H[1][0] * H[2][2] - H[1][2] * H[2][0])
                + H[0][2] * (H[1][0] * H[2][1] - H[1][1] * H[2][0]);
    double d2 = (detH < 0.0) ? -1.0 : 1.0;

    // R = V diag(1,1,d2) U^T
    double R[3][3];
    for (int i = 0; i < 3; i++)
        for (int j = 0; j < 3; j++)
            R[i][j] = Vs[i][0] * U[j][0] + Vs[i][1] * U[j][1] + d2 * Vs[i][2] * U[j][2];

    // t = tbar - R sbar ;  t_out = -R^T t
    double tv[3];
    for (int i = 0; i < 3; i++)
        tv[i] = mt[i] - (R[i][0] * ms[0] + R[i][1] * ms[1] + R[i][2] * ms[2]);
    double to[3];
    for (int i = 0; i < 3; i++)
        to[i] = -(R[0][i] * tv[0] + R[1][i] * tv[1] + R[2][i] * tv[2]);

    // outputs: Rt (B,3,3) then t_out (B,3), concatenated flat
    float* outR = out + (size_t)b * 9;
    for (int i = 0; i < 3; i++)
        for (int j = 0; j < 3; j++)
            outR[i * 3 + j] = (float)R[j][i];   // Rt[i][j] = R[j][i]
    float* outT = out + (size_t)BATCH * 9 + (size_t)b * 3;
    for (int i = 0; i < 3; i++) outT[i] = (float)to[i];
}

extern "C" void kernel_launch(void* const* d_in, const int* in_sizes, int n_in,
                              void* d_out, int out_size, void* d_ws, size_t ws_size,
                              hipStream_t stream)
{
    const float* src    = (const float*)d_in[0];
    const float* tgt    = (const float*)d_in[1];
    const float* weight = (const float*)d_in[2];
    float* out = (float*)d_out;
    float* ws  = (float*)d_ws;   // 256*22 floats of scratch

    svdhead_reduce<<<BATCH, NT, 0, stream>>>(src, tgt, weight, ws);
    svdhead_solve<<<1, 256, 0, stream>>>(ws, out);
}

// Round 2
// 435.560 us; speedup vs baseline: 1.0051x; 1.0051x over previous
//
#include <hip/hip_runtime.h>

#define BATCH 256
#define NPTS 65536
#define NT 256                  // threads per reduce block
#define SPLIT 8                 // blocks per batch
#define NWAVES (NT / 64)
#define CHUNKS_PER_BLOCK (NPTS / 4 / SPLIT)   // 2048 float4 chunks
#define ITERS (CHUNKS_PER_BLOCK / NT)         // 8 iterations per thread

// ---------------------------------------------------------------------------
// Stage 1: grid = BATCH*SPLIT blocks of 256 threads. Each block reduces a
// 1/SPLIT slice of one batch into 22 partial sums:
//  [0..2]=sum s_i  [3..5]=sum t_j  [6]=sum w
//  [7..9]=sum w*s_i [10..12]=sum w*t_j [13..21]=sum w*s_i*t_j (i*3+j)
// Deterministic partials: ws[(b*SPLIT+part)*22 + i].
// ---------------------------------------------------------------------------
__global__ __launch_bounds__(NT, 4) void svdhead_reduce(
    const float* __restrict__ src, const float* __restrict__ tgt,
    const float* __restrict__ weight, float* __restrict__ ws)
{
    const int b    = blockIdx.x / SPLIT;
    const int part = blockIdx.x % SPLIT;
    const int tid  = threadIdx.x;
    const int NV   = NPTS / 4;

    const float4* sp = (const float4*)(src + (size_t)b * 3 * NPTS);
    const float4* tp = (const float4*)(tgt + (size_t)b * 3 * NPTS);
    const float4* wp = (const float4*)(weight + (size_t)b * NPTS);

    float acc[22];
#pragma unroll
    for (int i = 0; i < 22; i++) acc[i] = 0.f;

    const int base = part * CHUNKS_PER_BLOCK + tid;

#pragma unroll 2
    for (int it = 0; it < ITERS; it++) {
        const int k = base + it * NT;
        float4 w4 = wp[k];
        float4 s0 = sp[k];
        float4 s1 = sp[k + NV];
        float4 s2 = sp[k + 2 * NV];
        float4 t0 = tp[k];
        float4 t1 = tp[k + NV];
        float4 t2 = tp[k + 2 * NV];
#define ACC1(C) do {                                                    \
        float wv = w4.C;                                                \
        float a0 = s0.C, a1 = s1.C, a2 = s2.C;                          \
        float c0 = t0.C, c1 = t1.C, c2 = t2.C;                          \
        acc[0] += a0;  acc[1] += a1;  acc[2] += a2;                     \
        acc[3] += c0;  acc[4] += c1;  acc[5] += c2;                     \
        acc[6] += wv;                                                   \
        float wa0 = wv * a0, wa1 = wv * a1, wa2 = wv * a2;              \
        acc[7]  += wa0; acc[8]  += wa1; acc[9]  += wa2;                 \
        acc[10] += wv * c0; acc[11] += wv * c1; acc[12] += wv * c2;     \
        acc[13] += wa0 * c0; acc[14] += wa0 * c1; acc[15] += wa0 * c2;  \
        acc[16] += wa1 * c0; acc[17] += wa1 * c1; acc[18] += wa1 * c2;  \
        acc[19] += wa2 * c0; acc[20] += wa2 * c1; acc[21] += wa2 * c2;  \
    } while (0)
        ACC1(x); ACC1(y); ACC1(z); ACC1(w);
#undef ACC1
    }

    // wave-level reduce (64 lanes)
#pragma unroll
    for (int off = 32; off > 0; off >>= 1) {
#pragma unroll
        for (int i = 0; i < 22; i++) acc[i] += __shfl_down(acc[i], off, 64);
    }

    __shared__ float red[NWAVES][22];
    const int wave = tid >> 6;
    const int lane = tid & 63;
    if (lane == 0) {
#pragma unroll
        for (int i = 0; i < 22; i++) red[wave][i] = acc[i];
    }
    __syncthreads();

    if (tid < 22) {
        float s = 0.f;
#pragma unroll
        for (int wv = 0; wv < NWAVES; wv++) s += red[wv][tid];
        ws[((size_t)b * SPLIT + part) * 22 + tid] = s;
    }
}

// ---------------------------------------------------------------------------
// Stage 2: grid = BATCH blocks of 64 threads; block b solves batch b.
// Lanes 0..21 sum the SPLIT partials (fp64) into LDS; lane 0 runs the fp64
// 3x3 Kabsch solve (Jacobi on H^T H -> V; U = HV/sigma w/ fallbacks;
// R = V diag(1,1,sign detH) U^T). Outputs R^T (B,3,3) then t_out (B,3).
// One independent dependent-chain per CU -> latency fully parallel.
// ---------------------------------------------------------------------------
__global__ __launch_bounds__(64, 1) void svdhead_solve(
    const float* __restrict__ ws, float* __restrict__ out)
{
    const int b   = blockIdx.x;
    const int tid = threadIdx.x;

    __shared__ double S[22];
    if (tid < 22) {
        double s = 0.0;
#pragma unroll
        for (int p = 0; p < SPLIT; p++)
            s += (double)ws[((size_t)b * SPLIT + p) * 22 + tid];
        S[tid] = s;
    }
    __syncthreads();
    if (tid != 0) return;

    const double invN = 1.0 / (double)NPTS;
    double ms[3] = { S[0] * invN, S[1] * invN, S[2] * invN };
    double mt[3] = { S[3] * invN, S[4] * invN, S[5] * invN };
    const double sw = S[6];

    double H[3][3];
    for (int i = 0; i < 3; i++)
        for (int j = 0; j < 3; j++)
            H[i][j] = S[13 + i * 3 + j] - ms[i] * S[10 + j] - mt[j] * S[7 + i]
                      + ms[i] * mt[j] * sw;

    // A = H^T H (symmetric PSD)
    double A[3][3];
    for (int i = 0; i < 3; i++)
        for (int j = 0; j < 3; j++) {
            double s = 0.0;
            for (int k = 0; k < 3; k++) s += H[k][i] * H[k][j];
            A[i][j] = s;
        }

    // cyclic Jacobi eigendecomposition, eigenvectors in columns of V
    double V[3][3] = { {1,0,0}, {0,1,0}, {0,0,1} };
    for (int sweep = 0; sweep < 30; sweep++) {
        double off  = fabs(A[0][1]) + fabs(A[0][2]) + fabs(A[1][2]);
        double diag = fabs(A[0][0]) + fabs(A[1][1]) + fabs(A[2][2]);
        if (off <= 1e-13 * diag || off == 0.0) break;
        for (int p = 0; p < 2; p++)
            for (int q = p + 1; q < 3; q++) {
                double apq = A[p][q];
                if (fabs(apq) < 1e-300) continue;
                double tau = (A[q][q] - A[p][p]) / (2.0 * apq);
                double t = (tau >= 0.0 ? 1.0 : -1.0) / (fabs(tau) + sqrt(1.0 + tau * tau));
                double c = 1.0 / sqrt(1.0 + t * t);
                double s_ = t * c;
                for (int k = 0; k < 3; k++) {
                    double akp = A[k][p], akq = A[k][q];
                    A[k][p] = c * akp - s_ * akq;
                    A[k][q] = s_ * akp + c * akq;
                }
                for (int k = 0; k < 3; k++) {
                    double apk = A[p][k], aqk = A[q][k];
                    A[p][k] = c * apk - s_ * aqk;
                    A[q][k] = s_ * apk + c * aqk;
                }
                for (int k = 0; k < 3; k++) {
                    double vkp = V[k][p], vkq = V[k][q];
                    V[k][p] = c * vkp - s_ * vkq;
                    V[k][q] = s_ * vkp + c * vkq;
                }
            }
    }

    // sort eigenvalues descending, permute V columns
    double lam[3] = { A[0][0], A[1][1], A[2][2] };
    int id[3] = { 0, 1, 2 };
    if (lam[id[0]] < lam[id[1]]) { int t = id[0]; id[0] = id[1]; id[1] = t; }
    if (lam[id[0]] < lam[id[2]]) { int t = id[0]; id[0] = id[2]; id[2] = t; }
    if (lam[id[1]] < lam[id[2]]) { int t = id[1]; id[1] = id[2]; id[2] = t; }
    double Vs[3][3];
    for (int k = 0; k < 3; k++)
        for (int i = 0; i < 3; i++) Vs[i][k] = V[i][id[k]];

    // U columns: u_k = H v_k / sigma_k
    double U[3][3], sig[3];
    for (int k = 0; k < 3; k++) {
        double u0 = H[0][0] * Vs[0][k] + H[0][1] * Vs[1][k] + H[0][2] * Vs[2][k];
        double u1 = H[1][0] * Vs[0][k] + H[1][1] * Vs[1][k] + H[1][2] * Vs[2][k];
        double u2 = H[2][0] * Vs[0][k] + H[2][1] * Vs[1][k] + H[2][2] * Vs[2][k];
        sig[k] = sqrt(u0 * u0 + u1 * u1 + u2 * u2);
        U[0][k] = u0; U[1][k] = u1; U[2][k] = u2;
    }
    double smax = (sig[0] > 1e-300) ? sig[0] : 1e-300;

    if (sig[0] > 0.0) {
        U[0][0] /= sig[0]; U[1][0] /= sig[0]; U[2][0] /= sig[0];
    } else {
        U[0][0] = 1; U[1][0] = 0; U[2][0] = 0;
    }
    if (sig[1] > 1e-12 * smax) {
        U[0][1] /= sig[1]; U[1][1] /= sig[1]; U[2][1] /= sig[1];
    } else {
        double ax = fabs(U[0][0]), ay = fabs(U[1][0]), az = fabs(U[2][0]);
        double e0, e1, e2;
        if (ax <= ay && ax <= az)      { e0 = 1; e1 = 0; e2 = 0; }
        else if (ay <= az)             { e0 = 0; e1 = 1; e2 = 0; }
        else                           { e0 = 0; e1 = 0; e2 = 1; }
        double cx = U[1][0] * e2 - U[2][0] * e1;
        double cy = U[2][0] * e0 - U[0][0] * e2;
        double cz = U[0][0] * e1 - U[1][0] * e0;
        double n = sqrt(cx * cx + cy * cy + cz * cz);
        U[0][1] = cx / n; U[1][1] = cy / n; U[2][1] = cz / n;
    }
    if (sig[2] > 1e-12 * smax) {
        U[0][2] /= sig[2]; U[1][2] /= sig[2]; U[2][2] /= sig[2];
    } else {
        U[0][2] = U[1][0] * U[2][1] - U[2][0] * U[1][1];
        U[1][2] = U[2][0] * U[0][1] - U[0][0] * U[2][1];
        U[2][2] = U[0][0] * U[1][1] - U[1][0] * U[0][1];
    }

    double detH = H[0][0] * (H[1][1] * H[2][2] - H[1][2] * H[2][1])
                - H[0][1] * (H[1][0] * H[2][2] - H[1][2] * H[2][0])
                + H[0][2] * (H[1][0] * H[2][1] - H[1][1] * H[2][0]);
    double d2 = (detH < 0.0) ? -1.0 : 1.0;

    // R = V diag(1,1,d2) U^T
    double R[3][3];
    for (int i = 0; i < 3; i++)
        for (int j = 0; j < 3; j++)
            R[i][j] = Vs[i][0] * U[j][0] + Vs[i][1] * U[j][1] + d2 * Vs[i][2] * U[j][2];

    // t = tbar - R sbar ;  t_out = -R^T t
    double tv[3];
    for (int i = 0; i < 3; i++)
        tv[i] = mt[i] - (R[i][0] * ms[0] + R[i][1] * ms[1] + R[i][2] * ms[2]);
    double to[3];
    for (int i = 0; i < 3; i++)
        to[i] = -(R[0][i] * tv[0] + R[1][i] * tv[1] + R[2][i] * tv[2]);

    float* outR = out + (size_t)b * 9;
    for (int i = 0; i < 3; i++)
        for (int j = 0; j < 3; j++)
            outR[i * 3 + j] = (float)R[j][i];   // Rt[i][j] = R[j][i]
    float* outT = out + (size_t)BATCH * 9 + (size_t)b * 3;
    for (int i = 0; i < 3; i++) outT[i] = (float)to[i];
}

extern "C" void kernel_launch(void* const* d_in, const int* in_sizes, int n_in,
                              void* d_out, int out_size, void* d_ws, size_t ws_size,
                              hipStream_t stream)
{
    const float* src    = (const float*)d_in[0];
    const float* tgt    = (const float*)d_in[1];
    const float* weight = (const float*)d_in[2];
    float* out = (float*)d_out;
    float* ws  = (float*)d_ws;   // BATCH*SPLIT*22 floats of scratch (~180 KB)

    svdhead_reduce<<<BATCH * SPLIT, NT, 0, stream>>>(src, tgt, weight, ws);
    svdhead_solve<<<BATCH, 64, 0, stream>>>(ws, out);
}

// Round 3
// 433.985 us; speedup vs baseline: 1.0088x; 1.0036x over previous
//
#include <hip/hip_runtime.h>

#define BATCH 256
#define NPTS 65536
#define NT 256                  // threads per reduce block
#define SPLIT 8                 // blocks per batch
#define NWAVES (NT / 64)
#define CHUNKS_PER_BLOCK (NPTS / 4 / SPLIT)   // 2048 float4 chunks
#define ITERS (CHUNKS_PER_BLOCK / NT)         // 8 iterations per thread

// ---------------------------------------------------------------------------
// Stage 1: grid = BATCH*SPLIT blocks of 256 threads. Each block reduces a
// 1/SPLIT slice of one batch into 22 partial sums:
//  [0..2]=sum s_i  [3..5]=sum t_j  [6]=sum w
//  [7..9]=sum w*s_i [10..12]=sum w*t_j [13..21]=sum w*s_i*t_j (i*3+j)
// Deterministic partials: ws[(b*SPLIT+part)*22 + i].
//
// R3: explicit double-buffered prefetch — issue next iteration's 7 float4
// loads BEFORE consuming current iteration, full unroll, 256-VGPR budget.
// Goal: >=14 KB of loads in flight per wave (R2's VGPR=52 showed the
// compiler was serializing loads into a ~1-2 KB window).
// ---------------------------------------------------------------------------
__global__ __launch_bounds__(NT, 2) void svdhead_reduce(
    const float* __restrict__ src, const float* __restrict__ tgt,
    const float* __restrict__ weight, float* __restrict__ ws)
{
    const int b    = blockIdx.x / SPLIT;
    const int part = blockIdx.x % SPLIT;
    const int tid  = threadIdx.x;
    const int NV   = NPTS / 4;

    const float4* sp = (const float4*)(src + (size_t)b * 3 * NPTS);
    const float4* tp = (const float4*)(tgt + (size_t)b * 3 * NPTS);
    const float4* wp = (const float4*)(weight + (size_t)b * NPTS);

    float acc[22];
#pragma unroll
    for (int i = 0; i < 22; i++) acc[i] = 0.f;

    const int base = part * CHUNKS_PER_BLOCK + tid;

    // prologue: load iteration 0
    int k = base;
    float4 cw  = wp[k];
    float4 cs0 = sp[k];
    float4 cs1 = sp[k + NV];
    float4 cs2 = sp[k + 2 * NV];
    float4 ct0 = tp[k];
    float4 ct1 = tp[k + NV];
    float4 ct2 = tp[k + 2 * NV];

#pragma unroll
    for (int it = 0; it < ITERS; it++) {
        float4 nw, ns0, ns1, ns2, nt0, nt1, nt2;
        if (it + 1 < ITERS) {               // issue next loads before use
            const int kn = k + NT;
            nw  = wp[kn];
            ns0 = sp[kn];
            ns1 = sp[kn + NV];
            ns2 = sp[kn + 2 * NV];
            nt0 = tp[kn];
            nt1 = tp[kn + NV];
            nt2 = tp[kn + 2 * NV];
        }
#define ACC1(C) do {                                                    \
        float wv = cw.C;                                                \
        float a0 = cs0.C, a1 = cs1.C, a2 = cs2.C;                       \
        float c0 = ct0.C, c1 = ct1.C, c2 = ct2.C;                       \
        acc[0] += a0;  acc[1] += a1;  acc[2] += a2;                     \
        acc[3] += c0;  acc[4] += c1;  acc[5] += c2;                     \
        acc[6] += wv;                                                   \
        float wa0 = wv * a0, wa1 = wv * a1, wa2 = wv * a2;              \
        acc[7]  += wa0; acc[8]  += wa1; acc[9]  += wa2;                 \
        acc[10] += wv * c0; acc[11] += wv * c1; acc[12] += wv * c2;     \
        acc[13] += wa0 * c0; acc[14] += wa0 * c1; acc[15] += wa0 * c2;  \
        acc[16] += wa1 * c0; acc[17] += wa1 * c1; acc[18] += wa1 * c2;  \
        acc[19] += wa2 * c0; acc[20] += wa2 * c1; acc[21] += wa2 * c2;  \
    } while (0)
        ACC1(x); ACC1(y); ACC1(z); ACC1(w);
#undef ACC1
        k += NT;
        cw = nw; cs0 = ns0; cs1 = ns1; cs2 = ns2;
        ct0 = nt0; ct1 = nt1; ct2 = nt2;
    }

    // wave-level reduce (64 lanes)
#pragma unroll
    for (int off = 32; off > 0; off >>= 1) {
#pragma unroll
        for (int i = 0; i < 22; i++) acc[i] += __shfl_down(acc[i], off, 64);
    }

    __shared__ float red[NWAVES][22];
    const int wave = tid >> 6;
    const int lane = tid & 63;
    if (lane == 0) {
#pragma unroll
        for (int i = 0; i < 22; i++) red[wave][i] = acc[i];
    }
    __syncthreads();

    if (tid < 22) {
        float s = 0.f;
#pragma unroll
        for (int wv = 0; wv < NWAVES; wv++) s += red[wv][tid];
        ws[((size_t)b * SPLIT + part) * 22 + tid] = s;
    }
}

// ---------------------------------------------------------------------------
// Stage 2: grid = BATCH blocks of 64 threads; block b solves batch b.
// Lanes 0..21 sum the SPLIT partials (fp64) into LDS; lane 0 runs the fp64
// 3x3 Kabsch solve (Jacobi on H^T H -> V; U = HV/sigma w/ fallbacks;
// R = V diag(1,1,sign detH) U^T). Outputs R^T (B,3,3) then t_out (B,3).
// ---------------------------------------------------------------------------
__global__ __launch_bounds__(64, 1) void svdhead_solve(
    const float* __restrict__ ws, float* __restrict__ out)
{
    const int b   = blockIdx.x;
    const int tid = threadIdx.x;

    __shared__ double S[22];
    if (tid < 22) {
        double s = 0.0;
#pragma unroll
        for (int p = 0; p < SPLIT; p++)
            s += (double)ws[((size_t)b * SPLIT + p) * 22 + tid];
        S[tid] = s;
    }
    __syncthreads();
    if (tid != 0) return;

    const double invN = 1.0 / (double)NPTS;
    double ms[3] = { S[0] * invN, S[1] * invN, S[2] * invN };
    double mt[3] = { S[3] * invN, S[4] * invN, S[5] * invN };
    const double sw = S[6];

    double H[3][3];
    for (int i = 0; i < 3; i++)
        for (int j = 0; j < 3; j++)
            H[i][j] = S[13 + i * 3 + j] - ms[i] * S[10 + j] - mt[j] * S[7 + i]
                      + ms[i] * mt[j] * sw;

    // A = H^T H (symmetric PSD)
    double A[3][3];
    for (int i = 0; i < 3; i++)
        for (int j = 0; j < 3; j++) {
            double s = 0.0;
            for (int k = 0; k < 3; k++) s += H[k][i] * H[k][j];
            A[i][j] = s;
        }

    // cyclic Jacobi eigendecomposition, eigenvectors in columns of V
    double V[3][3] = { {1,0,0}, {0,1,0}, {0,0,1} };
    for (int sweep = 0; sweep < 15; sweep++) {
        double off  = fabs(A[0][1]) + fabs(A[0][2]) + fabs(A[1][2]);
        double diag = fabs(A[0][0]) + fabs(A[1][1]) + fabs(A[2][2]);
        if (off <= 1e-13 * diag || off == 0.0) break;
        for (int p = 0; p < 2; p++)
            for (int q = p + 1; q < 3; q++) {
                double apq = A[p][q];
                if (fabs(apq) < 1e-300) continue;
                double tau = (A[q][q] - A[p][p]) / (2.0 * apq);
                double t = (tau >= 0.0 ? 1.0 : -1.0) / (fabs(tau) + sqrt(1.0 + tau * tau));
                double c = 1.0 / sqrt(1.0 + t * t);
                double s_ = t * c;
                for (int kk = 0; kk < 3; kk++) {
                    double akp = A[kk][p], akq = A[kk][q];
                    A[kk][p] = c * akp - s_ * akq;
                    A[kk][q] = s_ * akp + c * akq;
                }
                for (int kk = 0; kk < 3; kk++) {
                    double apk = A[p][kk], aqk = A[q][kk];
                    A[p][kk] = c * apk - s_ * aqk;
                    A[q][kk] = s_ * apk + c * aqk;
                }
                for (int kk = 0; kk < 3; kk++) {
                    double vkp = V[kk][p], vkq = V[kk][q];
                    V[kk][p] = c * vkp - s_ * vkq;
                    V[kk][q] = s_ * vkp + c * vkq;
                }
            }
    }

    // sort eigenvalues descending, permute V columns
    double lam[3] = { A[0][0], A[1][1], A[2][2] };
    int id[3] = { 0, 1, 2 };
    if (lam[id[0]] < lam[id[1]]) { int t = id[0]; id[0] = id[1]; id[1] = t; }
    if (lam[id[0]] < lam[id[2]]) { int t = id[0]; id[0] = id[2]; id[2] = t; }
    if (lam[id[1]] < lam[id[2]]) { int t = id[1]; id[1] = id[2]; id[2] = t; }
    double Vs[3][3];
    for (int k = 0; k < 3; k++)
        for (int i = 0; i < 3; i++) Vs[i][k] = V[i][id[k]];

    // U columns: u_k = H v_k / sigma_k
    double U[3][3], sig[3];
    for (int k = 0; k < 3; k++) {
        double u0 = H[0][0] * Vs[0][k] + H[0][1] * Vs[1][k] + H[0][2] * Vs[2][k];
        double u1 = H[1][0] * Vs[0][k] + H[1][1] * Vs[1][k] + H[1][2] * Vs[2][k];
        double u2 = H[2][0] * Vs[0][k] + H[2][1] * Vs[1][k] + H[2][2] * Vs[2][k];
        sig[k] = sqrt(u0 * u0 + u1 * u1 + u2 * u2);
        U[0][k] = u0; U[1][k] = u1; U[2][k] = u2;
    }
    double smax = (sig[0] > 1e-300) ? sig[0] : 1e-300;

    if (sig[0] > 0.0) {
        U[0][0] /= sig[0]; U[1][0] /= sig[0]; U[2][0] /= sig[0];
    } else {
        U[0][0] = 1; U[1][0] = 0; U[2][0] = 0;
    }
    if (sig[1] > 1e-12 * smax) {
        U[0][1] /= sig[1]; U[1][1] /= sig[1]; U[2][1] /= sig[1];
    } else {
        double ax = fabs(U[0][0]), ay = fabs(U[1][0]), az = fabs(U[2][0]);
        double e0, e1, e2;
        if (ax <= ay && ax <= az)      { e0 = 1; e1 = 0; e2 = 0; }
        else if (ay <= az)             { e0 = 0; e1 = 1; e2 = 0; }
        else                           { e0 = 0; e1 = 0; e2 = 1; }
        double cx = U[1][0] * e2 - U[2][0] * e1;
        double cy = U[2][0] * e0 - U[0][0] * e2;
        double cz = U[0][0] * e1 - U[1][0] * e0;
        double n = sqrt(cx * cx + cy * cy + cz * cz);
        U[0][1] = cx / n; U[1][1] = cy / n; U[2][1] = cz / n;
    }
    if (sig[2] > 1e-12 * smax) {
        U[0][2] /= sig[2]; U[1][2] /= sig[2]; U[2][2] /= sig[2];
    } else {
        U[0][2] = U[1][0] * U[2][1] - U[2][0] * U[1][1];
        U[1][2] = U[2][0] * U[0][1] - U[0][0] * U[2][1];
        U[2][2] = U[0][0] * U[1][1] - U[1][0] * U[0][1];
    }

    double detH = H[0][0] * (H[1][1] * H[2][2] - H[1][2] * H[2][1])
                - H[0][1] * (H[1][0] * H[2][2] - H[1][2] * H[2][0])
                + H[0][2] * (H[1][0] * H[2][1] - H[1][1] * H[2][0]);
    double d2 = (detH < 0.0) ? -1.0 : 1.0;

    // R = V diag(1,1,d2) U^T
    double R[3][3];
    for (int i = 0; i < 3; i++)
        for (int j = 0; j < 3; j++)
            R[i][j] = Vs[i][0] * U[j][0] + Vs[i][1] * U[j][1] + d2 * Vs[i][2] * U[j][2];

    // t = tbar - R sbar ;  t_out = -R^T t
    double tv[3];
    for (int i = 0; i < 3; i++)
        tv[i] = mt[i] - (R[i][0] * ms[0] + R[i][1] * ms[1] + R[i][2] * ms[2]);
    double to[3];
    for (int i = 0; i < 3; i++)
        to[i] = -(R[0][i] * tv[0] + R[1][i] * tv[1] + R[2][i] * tv[2]);

    float* outR = out + (size_t)b * 9;
    for (int i = 0; i < 3; i++)
        for (int j = 0; j < 3; j++)
            outR[i * 3 + j] = (float)R[j][i];   // Rt[i][j] = R[j][i]
    float* outT = out + (size_t)BATCH * 9 + (size_t)b * 3;
    for (int i = 0; i < 3; i++) outT[i] = (float)to[i];
}

extern "C" void kernel_launch(void* const* d_in, const int* in_sizes, int n_in,
                              void* d_out, int out_size, void* d_ws, size_t ws_size,
                              hipStream_t stream)
{
    const float* src    = (const float*)d_in[0];
    const float* tgt    = (const float*)d_in[1];
    const float* weight = (const float*)d_in[2];
    float* out = (float*)d_out;
    float* ws  = (float*)d_ws;   // BATCH*SPLIT*22 floats of scratch (~180 KB)

    svdhead_reduce<<<BATCH * SPLIT, NT, 0, stream>>>(src, tgt, weight, ws);
    svdhead_solve<<<BATCH, 64, 0, stream>>>(ws, out);
}